// Round 3
// baseline (293.249 us; speedup 1.0000x reference)
//
#include <hip/hip_runtime.h>
#include <cstdint>

#define Bb 4
#define Lseq 4096
#define Hh 1024
#define Nst 64
constexpr float LN_EPS = 1e-5f;

typedef _Float16 f16x8 __attribute__((ext_vector_type(8)));
typedef _Float16 f16x4 __attribute__((ext_vector_type(4)));
typedef float f32x4v __attribute__((ext_vector_type(4)));

// ---------------------------------------------------------------------------
// K0: precompute per-h 64x64 matrices (f16) into d_out scratch:
//   per h (5*4096 f16): [U_re | U_im | M1 (Tril K) | P_re | P_im_neg]
//   U[n][j]  = w_n^{63-j}
//   M1[t][j] = K[t-j] (j<=t), K[tau] = 2 Re sum_n Ct_n w_n^tau
//   P[t][n]  = Re/(-Im) of 2*Ct_n*w_n^{t+1}
// plus ww = w^64 (fp32) for the chunk-level scan.
// ---------------------------------------------------------------------------
__global__ __launch_bounds__(256) void k_precompute(
    const float* __restrict__ logA, const float* __restrict__ Aim,
    const float* __restrict__ Cre, const float* __restrict__ Cim,
    const float* __restrict__ logdt, _Float16* __restrict__ mats,
    float* __restrict__ wwR, float* __restrict__ wwI) {
    __shared__ float sdAr[64], sdAi[64], scR[64], scI[64], sK[64];
    const int h = blockIdx.x, tid = threadIdx.x;
    _Float16* g = mats + (size_t)h * 20480;

    if (tid < 64) {
        const int n = tid, idx = h * 64 + n;
        const float ar = -expf(logA[idx]), ai = Aim[idx];
        const float dt = expf(logdt[h]);
        const float dAr = dt * ar, dAi = dt * ai;
        const float em = expf(dAr);
        const float wr = em * cosf(dAi), wi = em * sinf(dAi);
        const float Er = wr - 1.0f, Ei = wi;
        const float cr = Cre[idx], ci = Cim[idx];
        const float nr = cr * Er - ci * Ei, ni = cr * Ei + ci * Er;
        const float invd = 1.0f / (ar * ar + ai * ai);
        const float CtR = (nr * ar + ni * ai) * invd;
        const float CtI = (ni * ar - nr * ai) * invd;
        sdAr[n] = dAr; sdAi[n] = dAi; scR[n] = 2.0f * CtR; scI[n] = 2.0f * CtI;
        const float e64 = expf(dAr * 64.0f), a64 = dAi * 64.0f;
        wwR[idx] = e64 * cosf(a64);
        wwI[idx] = e64 * sinf(a64);
    }
    __syncthreads();

    for (int e = tid; e < 4096; e += 256) {
        const int row = e >> 6, colj = e & 63;
        {
            const float p = (float)(63 - colj);
            const float ee = expf(sdAr[row] * p), ang = sdAi[row] * p;
            g[e]        = (_Float16)(ee * cosf(ang));
            g[4096 + e] = (_Float16)(ee * sinf(ang));
        }
        {
            const int n = colj;
            const float q = (float)(row + 1);
            const float ee = expf(sdAr[n] * q), ang = sdAi[n] * q;
            const float wRq = ee * cosf(ang), wIq = ee * sinf(ang);
            g[12288 + e] = (_Float16)(scR[n] * wRq - scI[n] * wIq);
            g[16384 + e] = (_Float16)(-(scR[n] * wIq + scI[n] * wRq));
        }
    }
    if (tid < 64) {
        const float tau = (float)tid;
        float sum = 0.0f;
        for (int n = 0; n < 64; ++n) {
            const float ee = expf(sdAr[n] * tau), ang = sdAi[n] * tau;
            sum += ee * (scR[n] * cosf(ang) - scI[n] * sinf(ang));
        }
        sK[tid] = sum;
    }
    __syncthreads();
    for (int e = tid; e < 4096; e += 256) {
        const int t = e >> 6, j = e & 63;
        g[8192 + e] = (j <= t) ? (_Float16)sK[t - j] : (_Float16)0.0f;
    }
}

// ---------------------------------------------------------------------------
// K1: transpose x [B, L, H] -> xt [B, H, L] (into ws).
// ---------------------------------------------------------------------------
__global__ __launch_bounds__(256) void k_transpose(const float* __restrict__ x,
                                                   float* __restrict__ xt) {
    __shared__ float tile[32][33];
    const int h0 = blockIdx.x * 32;
    const int l0 = blockIdx.y * 32;
    const int b  = blockIdx.z;
    const int tj = threadIdx.x & 31;
    const int ti = threadIdx.x >> 5;

    const float* src = x + ((size_t)b * Lseq + l0) * Hh + h0;
#pragma unroll
    for (int it = 0; it < 4; ++it) {
        int row = it * 8 + ti;
        tile[row][tj] = src[(size_t)row * Hh + tj];
    }
    __syncthreads();
    float* dst = xt + ((size_t)b * Hh + h0) * Lseq + l0;
#pragma unroll
    for (int it = 0; it < 4; ++it) {
        int row = it * 8 + ti;
        dst[(size_t)row * Lseq + tj] = tile[tj][row];
    }
}

// ---------------------------------------------------------------------------
// K2: chunked block-scan via MFMA, minimal-LDS version.
// A/B fragments loaded DIRECTLY from global (x fp32->f16; mats f16 16B runs).
// LDS only for: u (phase1->2), S (phase2->3), YF (phase3->epilogue, reuses u).
// 36,864B LDS -> 4 blocks/CU.
// ---------------------------------------------------------------------------
#define uRo 0        // f16 [64][72] stride 144B
#define uIo 9216
#define SRo 18432
#define SIo 27648
#define YFo 0        // reuses uRo (dead after phase 2)

// B/A fragment from a row-major [row][64] f16 matrix in global
#define GFRAG(p, row0, kk) \
    (*(const f16x8*)((p) + ((row0) + col) * 64 + (kk) + qd * 8))
// A fragment from LDS f16 [64][72]
#define LFRAG(base, row0, kk) \
    (*(const f16x8*)(sm + (base) + ((row0) + col) * 144 + ((kk) + qd * 8) * 2))

__global__ __launch_bounds__(256, 4) void k_chunk(
    float* __restrict__ xt, const _Float16* __restrict__ mats,
    const float* __restrict__ wwR, const float* __restrict__ wwI,
    const float* __restrict__ Dp) {
    __shared__ __align__(16) unsigned char sm[36864];
    const int tid = threadIdx.x, lane = tid & 63, wv = tid >> 6;
    const int bx = blockIdx.x, h = bx & (Hh - 1), b = bx >> 10;
    float* xr = xt + (size_t)(b * Hh + h) * Lseq;
    const _Float16* g = mats + (size_t)h * 20480;
    const int col = lane & 15, qd = lane >> 4;
    const int band = wv * 16;

    // ---- phase 1: u = X @ U^T (complex); X fragments from global ----
    f16x8 axk[2];
    f32x4v aR[4] = {}, aI[4] = {};
#pragma unroll
    for (int kh2 = 0; kh2 < 2; ++kh2) {
        const int kk = kh2 * 32;
        const float* xp = xr + (band + col) * 64 + kk + qd * 8;
        const float4 v0 = *(const float4*)(xp);
        const float4 v1 = *(const float4*)(xp + 4);
        f16x8 a;
        a[0] = (_Float16)v0.x; a[1] = (_Float16)v0.y;
        a[2] = (_Float16)v0.z; a[3] = (_Float16)v0.w;
        a[4] = (_Float16)v1.x; a[5] = (_Float16)v1.y;
        a[6] = (_Float16)v1.z; a[7] = (_Float16)v1.w;
        axk[kh2] = a;
#pragma unroll
        for (int nt = 0; nt < 4; ++nt) {
            aR[nt] = __builtin_amdgcn_mfma_f32_16x16x32_f16(
                a, GFRAG(g, nt * 16, kk), aR[nt], 0, 0, 0);
            aI[nt] = __builtin_amdgcn_mfma_f32_16x16x32_f16(
                a, GFRAG(g + 4096, nt * 16, kk), aI[nt], 0, 0, 0);
        }
    }
#pragma unroll
    for (int nt = 0; nt < 4; ++nt)
#pragma unroll
        for (int rg = 0; rg < 4; ++rg) {
            const int c = band + qd * 4 + rg, n = nt * 16 + col;
            *(_Float16*)(sm + uRo + c * 144 + n * 2) = (_Float16)aR[nt][rg];
            *(_Float16*)(sm + uIo + c * 144 + n * 2) = (_Float16)aI[nt][rg];
        }
    __syncthreads();

    // ---- phase 2: chunk-level scan (waves 0-1; lanes>=32 redundant) ----
    if (wv < 2) {
        const int n = wv * 32 + (lane & 31);
        const float wR = wwR[h * 64 + n], wI = wwI[h * 64 + n];
        float sR = 0.0f, sI = 0.0f;
        for (int c = 0; c < 64; ++c) {
            if (lane < 32) {
                *(_Float16*)(sm + SRo + c * 144 + n * 2) = (_Float16)sR;
                *(_Float16*)(sm + SIo + c * 144 + n * 2) = (_Float16)sI;
            }
            const float uRv = (float)*(const _Float16*)(sm + uRo + c * 144 + n * 2);
            const float uIv = (float)*(const _Float16*)(sm + uIo + c * 144 + n * 2);
            const float nR = fmaf(wR, sR, fmaf(-wI, sI, uRv));
            sI = fmaf(wR, sI, fmaf(wI, sR, uIv));
            sR = nR;
        }
    }
    __syncthreads();

    // ---- phase 3: y = X@M1^T + SR@PR^T + SI@PIneg^T ----
    f32x4v acc[4] = {};
#pragma unroll
    for (int kh2 = 0; kh2 < 2; ++kh2) {
        const int kk = kh2 * 32;
#pragma unroll
        for (int tt = 0; tt < 4; ++tt)
            acc[tt] = __builtin_amdgcn_mfma_f32_16x16x32_f16(
                axk[kh2], GFRAG(g + 8192, tt * 16, kk), acc[tt], 0, 0, 0);
    }
#pragma unroll
    for (int kh2 = 0; kh2 < 2; ++kh2) {
        const int kk = kh2 * 32;
        const f16x8 as = LFRAG(SRo, band, kk);
#pragma unroll
        for (int tt = 0; tt < 4; ++tt)
            acc[tt] = __builtin_amdgcn_mfma_f32_16x16x32_f16(
                as, GFRAG(g + 12288, tt * 16, kk), acc[tt], 0, 0, 0);
    }
#pragma unroll
    for (int kh2 = 0; kh2 < 2; ++kh2) {
        const int kk = kh2 * 32;
        const f16x8 az = LFRAG(SIo, band, kk);
#pragma unroll
        for (int tt = 0; tt < 4; ++tt)
            acc[tt] = __builtin_amdgcn_mfma_f32_16x16x32_f16(
                az, GFRAG(g + 16384, tt * 16, kk), acc[tt], 0, 0, 0);
    }
    __syncthreads();  // uRo region dead for ALL waves before YF overwrite
#pragma unroll
    for (int tt = 0; tt < 4; ++tt)
#pragma unroll
        for (int rg = 0; rg < 4; ++rg) {
            const int c = band + qd * 4 + rg, t = tt * 16 + col;
            *(_Float16*)(sm + YFo + c * 144 + t * 2) = (_Float16)acc[tt][rg];
        }
    __syncthreads();

    // ---- epilogue: r = x*(1+D) + y, in-place ----
    const float Dp1 = 1.0f + Dp[h];
#pragma unroll
    for (int r = 0; r < 4; ++r) {
        const int idx = r * 1024 + tid * 4;
        const int c = idx >> 6, j = idx & 63;
        const float4 xv = *(const float4*)(xr + idx);
        const f16x4 yv = *(const f16x4*)(sm + YFo + c * 144 + j * 2);
        float4 o;
        o.x = fmaf(xv.x, Dp1, (float)yv[0]);
        o.y = fmaf(xv.y, Dp1, (float)yv[1]);
        o.z = fmaf(xv.z, Dp1, (float)yv[2]);
        o.w = fmaf(xv.w, Dp1, (float)yv[3]);
        *(float4*)(xr + idx) = o;
    }
}

// ---------------------------------------------------------------------------
// K3: single-pass LayerNorm + transpose back: rt [B,H,L] -> out [B,L,H].
// Block = 512 threads handles (b, 16 l): cache tile [16][1032] in LDS,
// stats, then normalize from LDS with fully-coalesced h-major stores.
// LDS ~70KB -> 2 blocks/CU.
// ---------------------------------------------------------------------------
__global__ __launch_bounds__(512, 2) void k_ln(const float* __restrict__ rt,
                                               float* __restrict__ out,
                                               const float* __restrict__ lnw,
                                               const float* __restrict__ lnb) {
    __shared__ float tile[16 * 1032];
    __shared__ float ps[32][17], pq[32][17];
    __shared__ float mm[16], rs[16];
    const int b  = blockIdx.y;
    const int l0 = blockIdx.x * 16;
    const int tid = threadIdx.x;
    const int ll = tid & 15;
    const int hh = tid >> 4;  // 0..31

    const float* base = rt + (size_t)b * Hh * Lseq + l0;

    float psum = 0.0f, psq = 0.0f;
#pragma unroll 8
    for (int hc = 0; hc < Hh; hc += 32) {
        const float v = base[(size_t)(hc + hh) * Lseq + ll];
        tile[ll * 1032 + hc + hh] = v;
        psum += v;
        psq = fmaf(v, v, psq);
    }
    ps[hh][ll] = psum;
    pq[hh][ll] = psq;
    __syncthreads();
    if (tid < 16) {
        float s = 0.f, q = 0.f;
#pragma unroll
        for (int k = 0; k < 32; ++k) {
            s += ps[k][tid];
            q += pq[k][tid];
        }
        const float mu  = s * (1.0f / Hh);
        const float var = fmaf(-mu, mu, q * (1.0f / Hh));
        mm[tid] = mu;
        rs[tid] = rsqrtf(var + LN_EPS);
    }
    __syncthreads();

    const float w0 = lnw[tid],       b0 = lnb[tid];
    const float w1 = lnw[512 + tid], b1 = lnb[512 + tid];
    float* obase = out + ((size_t)b * Lseq + l0) * Hh;
#pragma unroll 4
    for (int l = 0; l < 16; ++l) {
        const float mu = mm[l], rsg = rs[l];
        const float v0 = tile[l * 1032 + tid];
        const float v1 = tile[l * 1032 + 512 + tid];
        obase[(size_t)l * Hh + tid]       = fmaf((v0 - mu) * rsg, w0, b0);
        obase[(size_t)l * Hh + 512 + tid] = fmaf((v1 - mu) * rsg, w1, b1);
    }
}

// ---------------------------------------------------------------------------
extern "C" void kernel_launch(void* const* d_in, const int* in_sizes, int n_in,
                              void* d_out, int out_size, void* d_ws, size_t ws_size,
                              hipStream_t stream) {
    const float* x     = (const float*)d_in[0];
    const float* logA  = (const float*)d_in[1];
    const float* Aim   = (const float*)d_in[2];
    const float* Cre   = (const float*)d_in[3];
    const float* Cim   = (const float*)d_in[4];
    const float* logdt = (const float*)d_in[5];
    const float* Dp    = (const float*)d_in[6];
    const float* lnw   = (const float*)d_in[7];
    const float* lnb   = (const float*)d_in[8];
    float* out = (float*)d_out;
    float* ws  = (float*)d_ws;  // 64 MiB: xt/r [B,H,L]

    _Float16* mats = (_Float16*)d_out;                          // 40 MiB
    float* wwR = (float*)((char*)d_out + 41943040);             // 256 KiB
    float* wwI = (float*)((char*)d_out + 42205184);             // 256 KiB

    k_precompute<<<dim3(Hh), 256, 0, stream>>>(logA, Aim, Cre, Cim, logdt,
                                               mats, wwR, wwI);
    k_transpose<<<dim3(Hh / 32, Lseq / 32, Bb), 256, 0, stream>>>(x, ws);
    k_chunk<<<dim3(Bb * Hh), 256, 0, stream>>>(ws, mats, wwR, wwI, Dp);
    k_ln<<<dim3(Lseq / 16, Bb), 512, 0, stream>>>(ws, out, lnw, lnb);
}

// Round 4
// 235.908 us; speedup vs baseline: 1.2431x; 1.2431x over previous
//
#include <hip/hip_runtime.h>
#include <cstdint>

#define Bb 4
#define Lseq 4096
#define Hh 1024
#define Nst 64
constexpr float LN_EPS = 1e-5f;

typedef _Float16 f16x8 __attribute__((ext_vector_type(8)));
typedef _Float16 f16x4 __attribute__((ext_vector_type(4)));
typedef float f32x4v __attribute__((ext_vector_type(4)));

// ---------------------------------------------------------------------------
// K0: precompute per-h 64x64 matrices (f16) into d_out scratch.
// Uses fast HW transcendentals (__expf/__sincosf) — libm sinf/cosf argument
// reduction was ~100us of the round-2/3 wall time.
//   per h (5*4096 f16): [U_re | U_im | M1 (Tril K) | P_re | P_im_neg]
// ---------------------------------------------------------------------------
__global__ __launch_bounds__(256) void k_precompute(
    const float* __restrict__ logA, const float* __restrict__ Aim,
    const float* __restrict__ Cre, const float* __restrict__ Cim,
    const float* __restrict__ logdt, _Float16* __restrict__ mats,
    float* __restrict__ wwR, float* __restrict__ wwI) {
    __shared__ float sdAr[64], sdAi[64], scR[64], scI[64], sK[64];
    const int h = blockIdx.x, tid = threadIdx.x;
    _Float16* g = mats + (size_t)h * 20480;

    if (tid < 64) {
        const int n = tid, idx = h * 64 + n;
        const float ar = -__expf(logA[idx]), ai = Aim[idx];
        const float dt = __expf(logdt[h]);
        const float dAr = dt * ar, dAi = dt * ai;
        float sn, cs;
        __sincosf(dAi, &sn, &cs);
        const float em = __expf(dAr);
        const float wr = em * cs, wi = em * sn;
        const float Er = wr - 1.0f, Ei = wi;
        const float cr = Cre[idx], ci = Cim[idx];
        const float nr = cr * Er - ci * Ei, ni = cr * Ei + ci * Er;
        const float invd = 1.0f / (ar * ar + ai * ai);
        const float CtR = (nr * ar + ni * ai) * invd;
        const float CtI = (ni * ar - nr * ai) * invd;
        sdAr[n] = dAr; sdAi[n] = dAi; scR[n] = 2.0f * CtR; scI[n] = 2.0f * CtI;
        float sn2, cs2;
        __sincosf(dAi * 64.0f, &sn2, &cs2);
        const float e64 = __expf(dAr * 64.0f);
        wwR[idx] = e64 * cs2;
        wwI[idx] = e64 * sn2;
    }
    __syncthreads();

    for (int e = tid; e < 4096; e += 256) {
        const int row = e >> 6, colj = e & 63;
        {
            const float p = (float)(63 - colj);
            float sn, cs;
            __sincosf(sdAi[row] * p, &sn, &cs);
            const float ee = __expf(sdAr[row] * p);
            g[e]        = (_Float16)(ee * cs);
            g[4096 + e] = (_Float16)(ee * sn);
        }
        {
            const int n = colj;
            const float q = (float)(row + 1);
            float sn, cs;
            __sincosf(sdAi[n] * q, &sn, &cs);
            const float ee = __expf(sdAr[n] * q);
            const float wRq = ee * cs, wIq = ee * sn;
            g[12288 + e] = (_Float16)(scR[n] * wRq - scI[n] * wIq);
            g[16384 + e] = (_Float16)(-(scR[n] * wIq + scI[n] * wRq));
        }
    }
    if (tid < 64) {
        const float tau = (float)tid;
        float sum = 0.0f;
        for (int n = 0; n < 64; ++n) {
            float sn, cs;
            __sincosf(sdAi[n] * tau, &sn, &cs);
            const float ee = __expf(sdAr[n] * tau);
            sum += ee * (scR[n] * cs - scI[n] * sn);
        }
        sK[tid] = sum;
    }
    __syncthreads();
    for (int e = tid; e < 4096; e += 256) {
        const int t = e >> 6, j = e & 63;
        g[8192 + e] = (j <= t) ? (_Float16)sK[t - j] : (_Float16)0.0f;
    }
}

// ---------------------------------------------------------------------------
// K1: transpose x [B, L, H] -> xt [B, H, L] (into ws).
// ---------------------------------------------------------------------------
__global__ __launch_bounds__(256) void k_transpose(const float* __restrict__ x,
                                                   float* __restrict__ xt) {
    __shared__ float tile[32][33];
    const int h0 = blockIdx.x * 32;
    const int l0 = blockIdx.y * 32;
    const int b  = blockIdx.z;
    const int tj = threadIdx.x & 31;
    const int ti = threadIdx.x >> 5;

    const float* src = x + ((size_t)b * Lseq + l0) * Hh + h0;
#pragma unroll
    for (int it = 0; it < 4; ++it) {
        int row = it * 8 + ti;
        tile[row][tj] = src[(size_t)row * Hh + tj];
    }
    __syncthreads();
    float* dst = xt + ((size_t)b * Hh + h0) * Lseq + l0;
#pragma unroll
    for (int it = 0; it < 4; ++it) {
        int row = it * 8 + ti;
        dst[(size_t)row * Lseq + tj] = tile[tj][row];
    }
}

// ---------------------------------------------------------------------------
// K2: chunked block-scan via MFMA. ONE BLOCK PER h (grid=1024), loop b=0..3.
// Mats staged into padded LDS once per block (40KB -> B-frags from LDS, mats
// HBM traffic 40MB total). u/S share one LDS buffer (in-place scan). Epilogue
// written directly from accumulators. LDS 64,512B -> 2 blocks/CU.
// ---------------------------------------------------------------------------
#define MR0 0        // U_re   f16 [64][72] stride 144B
#define MI0 9216     // U_im
#define MM1 18432    // M1
#define MPR 27648    // P_re
#define MPI 36864    // P_im_neg
#define uRo 46080    // u/S re (in-place)
#define uIo 55296    // u/S im

#define LFRAG(base, row0, kk) \
    (*(const f16x8*)(sm + (base) + ((row0) + col) * 144 + ((kk) + qd * 8) * 2))

__global__ __launch_bounds__(256, 2) void k_chunk(
    float* __restrict__ xt, const _Float16* __restrict__ mats,
    const float* __restrict__ wwR, const float* __restrict__ wwI,
    const float* __restrict__ Dp) {
    __shared__ __align__(16) unsigned char sm[64512];
    const int tid = threadIdx.x, lane = tid & 63, wv = tid >> 6;
    const int h = blockIdx.x;
    const _Float16* g = mats + (size_t)h * 20480;
    const int col = lane & 15, qd = lane >> 4;
    const int band = wv * 16;

    // ---- stage all 5 mats (40KB) into padded LDS, once ----
#pragma unroll
    for (int it = 0; it < 10; ++it) {
        const int chunk = it * 256 + tid;   // 16B units, 0..2559
        const int m = chunk >> 9;           // which matrix
        const int rem = chunk & 511;
        const int r = rem >> 3, c16 = rem & 7;
        *(uint4*)(sm + m * 9216 + r * 144 + c16 * 16) =
            *(const uint4*)(g + (size_t)chunk * 8);
    }

    const float Dp1 = 1.0f + Dp[h];
    float swR = 0.0f, swI = 0.0f;
    if (lane < 16) {
        swR = wwR[h * 64 + wv * 16 + lane];
        swI = wwI[h * 64 + wv * 16 + lane];
    }
    __syncthreads();

    for (int b = 0; b < Bb; ++b) {
        float* xr = xt + ((size_t)b * Hh + h) * Lseq;

        // ---- phase 1: u = X @ U^T (complex); X from global -> registers ----
        f16x8 axk[2];
        f32x4v aR[4] = {}, aI[4] = {};
#pragma unroll
        for (int kh2 = 0; kh2 < 2; ++kh2) {
            const int kk = kh2 * 32;
            const float* xp = xr + (band + col) * 64 + kk + qd * 8;
            const float4 v0 = *(const float4*)(xp);
            const float4 v1 = *(const float4*)(xp + 4);
            f16x8 a;
            a[0] = (_Float16)v0.x; a[1] = (_Float16)v0.y;
            a[2] = (_Float16)v0.z; a[3] = (_Float16)v0.w;
            a[4] = (_Float16)v1.x; a[5] = (_Float16)v1.y;
            a[6] = (_Float16)v1.z; a[7] = (_Float16)v1.w;
            axk[kh2] = a;
#pragma unroll
            for (int nt = 0; nt < 4; ++nt) {
                aR[nt] = __builtin_amdgcn_mfma_f32_16x16x32_f16(
                    a, LFRAG(MR0, nt * 16, kk), aR[nt], 0, 0, 0);
                aI[nt] = __builtin_amdgcn_mfma_f32_16x16x32_f16(
                    a, LFRAG(MI0, nt * 16, kk), aI[nt], 0, 0, 0);
            }
        }
        __syncthreads();  // (A) prev-b phase-3 S reads complete
#pragma unroll
        for (int nt = 0; nt < 4; ++nt)
#pragma unroll
            for (int rg = 0; rg < 4; ++rg) {
                const int c = band + qd * 4 + rg, n = nt * 16 + col;
                *(_Float16*)(sm + uRo + c * 144 + n * 2) = (_Float16)aR[nt][rg];
                *(_Float16*)(sm + uIo + c * 144 + n * 2) = (_Float16)aI[nt][rg];
            }
        __syncthreads();  // (B) u visible

        // ---- phase 2: chunk-level scan, in-place u->S; wave wv owns 16 n ----
        if (lane < 16) {
            const int n = wv * 16 + lane;
            float sR = 0.0f, sI = 0.0f;
            for (int c = 0; c < 64; ++c) {
                _Float16* pR = (_Float16*)(sm + uRo + c * 144 + n * 2);
                _Float16* pI = (_Float16*)(sm + uIo + c * 144 + n * 2);
                const float uRv = (float)*pR;
                const float uIv = (float)*pI;
                *pR = (_Float16)sR;
                *pI = (_Float16)sI;
                const float nR = fmaf(swR, sR, fmaf(-swI, sI, uRv));
                sI = fmaf(swR, sI, fmaf(swI, sR, uIv));
                sR = nR;
            }
        }
        __syncthreads();  // (C) S visible

        // ---- phase 3: y = X@M1^T + SR@PR^T + SI@PIneg^T ----
        f32x4v acc[4] = {};
#pragma unroll
        for (int kh2 = 0; kh2 < 2; ++kh2) {
            const int kk = kh2 * 32;
#pragma unroll
            for (int tt = 0; tt < 4; ++tt)
                acc[tt] = __builtin_amdgcn_mfma_f32_16x16x32_f16(
                    axk[kh2], LFRAG(MM1, tt * 16, kk), acc[tt], 0, 0, 0);
        }
#pragma unroll
        for (int kh2 = 0; kh2 < 2; ++kh2) {
            const int kk = kh2 * 32;
            const f16x8 as = LFRAG(uRo, band, kk);
#pragma unroll
            for (int tt = 0; tt < 4; ++tt)
                acc[tt] = __builtin_amdgcn_mfma_f32_16x16x32_f16(
                    as, LFRAG(MPR, tt * 16, kk), acc[tt], 0, 0, 0);
        }
#pragma unroll
        for (int kh2 = 0; kh2 < 2; ++kh2) {
            const int kk = kh2 * 32;
            const f16x8 az = LFRAG(uIo, band, kk);
#pragma unroll
            for (int tt = 0; tt < 4; ++tt)
                acc[tt] = __builtin_amdgcn_mfma_f32_16x16x32_f16(
                    az, LFRAG(MPI, tt * 16, kk), acc[tt], 0, 0, 0);
        }

        // ---- epilogue: r = x*(1+D) + y, straight from accumulators ----
#pragma unroll
        for (int tt = 0; tt < 4; ++tt)
#pragma unroll
            for (int rg = 0; rg < 4; ++rg) {
                const int l = (band + qd * 4 + rg) * 64 + tt * 16 + col;
                xr[l] = fmaf(xr[l], Dp1, acc[tt][rg]);
            }
    }
}

// ---------------------------------------------------------------------------
// K3: single-pass LayerNorm + transpose back: rt [B,H,L] -> out [B,L,H].
// ---------------------------------------------------------------------------
__global__ __launch_bounds__(512, 2) void k_ln(const float* __restrict__ rt,
                                               float* __restrict__ out,
                                               const float* __restrict__ lnw,
                                               const float* __restrict__ lnb) {
    __shared__ float tile[16 * 1032];
    __shared__ float ps[32][17], pq[32][17];
    __shared__ float mm[16], rs[16];
    const int b  = blockIdx.y;
    const int l0 = blockIdx.x * 16;
    const int tid = threadIdx.x;
    const int ll = tid & 15;
    const int hh = tid >> 4;  // 0..31

    const float* base = rt + (size_t)b * Hh * Lseq + l0;

    float psum = 0.0f, psq = 0.0f;
#pragma unroll 8
    for (int hc = 0; hc < Hh; hc += 32) {
        const float v = base[(size_t)(hc + hh) * Lseq + ll];
        tile[ll * 1032 + hc + hh] = v;
        psum += v;
        psq = fmaf(v, v, psq);
    }
    ps[hh][ll] = psum;
    pq[hh][ll] = psq;
    __syncthreads();
    if (tid < 16) {
        float s = 0.f, q = 0.f;
#pragma unroll
        for (int k = 0; k < 32; ++k) {
            s += ps[k][tid];
            q += pq[k][tid];
        }
        const float mu  = s * (1.0f / Hh);
        const float var = fmaf(-mu, mu, q * (1.0f / Hh));
        mm[tid] = mu;
        rs[tid] = rsqrtf(var + LN_EPS);
    }
    __syncthreads();

    const float w0 = lnw[tid],       b0 = lnb[tid];
    const float w1 = lnw[512 + tid], b1 = lnb[512 + tid];
    float* obase = out + ((size_t)b * Lseq + l0) * Hh;
#pragma unroll 4
    for (int l = 0; l < 16; ++l) {
        const float mu = mm[l], rsg = rs[l];
        const float v0 = tile[l * 1032 + tid];
        const float v1 = tile[l * 1032 + 512 + tid];
        obase[(size_t)l * Hh + tid]       = fmaf((v0 - mu) * rsg, w0, b0);
        obase[(size_t)l * Hh + 512 + tid] = fmaf((v1 - mu) * rsg, w1, b1);
    }
}

// ---------------------------------------------------------------------------
extern "C" void kernel_launch(void* const* d_in, const int* in_sizes, int n_in,
                              void* d_out, int out_size, void* d_ws, size_t ws_size,
                              hipStream_t stream) {
    const float* x     = (const float*)d_in[0];
    const float* logA  = (const float*)d_in[1];
    const float* Aim   = (const float*)d_in[2];
    const float* Cre   = (const float*)d_in[3];
    const float* Cim   = (const float*)d_in[4];
    const float* logdt = (const float*)d_in[5];
    const float* Dp    = (const float*)d_in[6];
    const float* lnw   = (const float*)d_in[7];
    const float* lnb   = (const float*)d_in[8];
    float* out = (float*)d_out;
    float* ws  = (float*)d_ws;  // 64 MiB: xt/r [B,H,L]

    _Float16* mats = (_Float16*)d_out;                          // 40 MiB
    float* wwR = (float*)((char*)d_out + 41943040);             // 256 KiB
    float* wwI = (float*)((char*)d_out + 42205184);             // 256 KiB

    k_precompute<<<dim3(Hh), 256, 0, stream>>>(logA, Aim, Cre, Cim, logdt,
                                               mats, wwR, wwI);
    k_transpose<<<dim3(Hh / 32, Lseq / 32, Bb), 256, 0, stream>>>(x, ws);
    k_chunk<<<dim3(Hh), 256, 0, stream>>>(ws, mats, wwR, wwI, Dp);
    k_ln<<<dim3(Lseq / 16, Bb), 512, 0, stream>>>(ws, out, lnw, lnb);
}

// Round 5
// 233.375 us; speedup vs baseline: 1.2566x; 1.0109x over previous
//
#include <hip/hip_runtime.h>
#include <cstdint>

#define Bb 4
#define Lseq 4096
#define Hh 1024
#define Nst 64
constexpr float LN_EPS = 1e-5f;

typedef _Float16 f16x8 __attribute__((ext_vector_type(8)));
typedef _Float16 f16x4 __attribute__((ext_vector_type(4)));
typedef float f32x4v __attribute__((ext_vector_type(4)));

// ---------------------------------------------------------------------------
// K0: precompute per-h 64x64 matrices (f16) into d_out scratch.
// __sinf/__cosf/__expf -> native v_sin/v_cos/v_exp (no libm argument
// reduction; __sincosf in R4 did NOT hit the native path).
//   per h (5*4096 f16): [U_re | U_im | M1 (Tril K) | P_re | P_im_neg]
// ---------------------------------------------------------------------------
__global__ __launch_bounds__(256) void k_precompute(
    const float* __restrict__ logA, const float* __restrict__ Aim,
    const float* __restrict__ Cre, const float* __restrict__ Cim,
    const float* __restrict__ logdt, _Float16* __restrict__ mats,
    float* __restrict__ wwR, float* __restrict__ wwI) {
    __shared__ float sdAr[64], sdAi[64], scR[64], scI[64], sK[64];
    const int h = blockIdx.x, tid = threadIdx.x;
    _Float16* g = mats + (size_t)h * 20480;

    if (tid < 64) {
        const int n = tid, idx = h * 64 + n;
        const float ar = -__expf(logA[idx]), ai = Aim[idx];
        const float dt = __expf(logdt[h]);
        const float dAr = dt * ar, dAi = dt * ai;
        const float em = __expf(dAr);
        const float wr = em * __cosf(dAi), wi = em * __sinf(dAi);
        const float Er = wr - 1.0f, Ei = wi;
        const float cr = Cre[idx], ci = Cim[idx];
        const float nr = cr * Er - ci * Ei, ni = cr * Ei + ci * Er;
        const float invd = 1.0f / (ar * ar + ai * ai);
        const float CtR = (nr * ar + ni * ai) * invd;
        const float CtI = (ni * ar - nr * ai) * invd;
        sdAr[n] = dAr; sdAi[n] = dAi; scR[n] = 2.0f * CtR; scI[n] = 2.0f * CtI;
        const float e64 = __expf(dAr * 64.0f), a64 = dAi * 64.0f;
        wwR[idx] = e64 * __cosf(a64);
        wwI[idx] = e64 * __sinf(a64);
    }
    __syncthreads();

    for (int e = tid; e < 4096; e += 256) {
        const int row = e >> 6, colj = e & 63;
        {
            const float p = (float)(63 - colj);
            const float ee = __expf(sdAr[row] * p), ang = sdAi[row] * p;
            g[e]        = (_Float16)(ee * __cosf(ang));
            g[4096 + e] = (_Float16)(ee * __sinf(ang));
        }
        {
            const int n = colj;
            const float q = (float)(row + 1);
            const float ee = __expf(sdAr[n] * q), ang = sdAi[n] * q;
            const float wRq = ee * __cosf(ang), wIq = ee * __sinf(ang);
            g[12288 + e] = (_Float16)(scR[n] * wRq - scI[n] * wIq);
            g[16384 + e] = (_Float16)(-(scR[n] * wIq + scI[n] * wRq));
        }
    }
    if (tid < 64) {
        const float tau = (float)tid;
        float sum = 0.0f;
        for (int n = 0; n < 64; ++n) {
            const float ee = __expf(sdAr[n] * tau), ang = sdAi[n] * tau;
            sum += ee * (scR[n] * __cosf(ang) - scI[n] * __sinf(ang));
        }
        sK[tid] = sum;
    }
    __syncthreads();
    for (int e = tid; e < 4096; e += 256) {
        const int t = e >> 6, j = e & 63;
        g[8192 + e] = (j <= t) ? (_Float16)sK[t - j] : (_Float16)0.0f;
    }
}

// ---------------------------------------------------------------------------
// K1: transpose x [B, L, H] -> xt [B, H, L]. 64x64 tiles, float4 both ways.
// LDS stride 65 (odd): max 2-way bank aliasing (free).
// ---------------------------------------------------------------------------
__global__ __launch_bounds__(256) void k_transpose(const float* __restrict__ x,
                                                   float* __restrict__ xt) {
    __shared__ float tile[64 * 65];   // [h][l]
    const int h0 = blockIdx.x * 64, l0 = blockIdx.y * 64, b = blockIdx.z;
    const int c = threadIdx.x & 15, r = threadIdx.x >> 4;

    const float* src = x + ((size_t)(b * Lseq + l0 + r)) * Hh + h0 + 4 * c;
#pragma unroll
    for (int it = 0; it < 4; ++it) {
        const float4 v = *(const float4*)(src + (size_t)it * 16 * Hh);
        const int l = it * 16 + r;
        tile[(4 * c + 0) * 65 + l] = v.x;
        tile[(4 * c + 1) * 65 + l] = v.y;
        tile[(4 * c + 2) * 65 + l] = v.z;
        tile[(4 * c + 3) * 65 + l] = v.w;
    }
    __syncthreads();
    float* dst = xt + ((size_t)(b * Hh + h0 + r)) * Lseq + l0 + 4 * c;
#pragma unroll
    for (int it = 0; it < 4; ++it) {
        const float* trow = tile + (it * 16 + r) * 65 + 4 * c;
        float4 o;
        o.x = trow[0]; o.y = trow[1]; o.z = trow[2]; o.w = trow[3];
        *(float4*)(dst + (size_t)it * 16 * Lseq) = o;
    }
}

// ---------------------------------------------------------------------------
// K2: chunked block-scan via MFMA. ONE 1024-THREAD BLOCK PER h; the four
// 4-wave groups process the four batches CONCURRENTLY. Mats staged once
// (46KB), per-batch u/S buffers (4x18KB). 117KB LDS -> 1 block/CU but
// 16 waves/CU; 3 block-wide barriers total (was 12).
// ---------------------------------------------------------------------------
#define MR0 0        // U_re   f16 [64][72] stride 144B
#define MI0 9216     // U_im
#define MM1 18432    // M1
#define MPR 27648    // P_re
#define MPI 36864    // P_im_neg
#define USB 46080    // 4 x { uR/S_R [64][72], uI/S_I [64][72] }

#define LFRAG(base, row0, kk) \
    (*(const f16x8*)(sm + (base) + ((row0) + col) * 144 + ((kk) + qd * 8) * 2))

__global__ __launch_bounds__(1024, 4) void k_chunk(
    float* __restrict__ xt, const _Float16* __restrict__ mats,
    const float* __restrict__ wwR, const float* __restrict__ wwI,
    const float* __restrict__ Dp) {
    __shared__ __align__(16) unsigned char sm[119808];
    const int tid = threadIdx.x, lane = tid & 63, wv = tid >> 6;
    const int grp = wv >> 2;          // batch index 0..3
    const int wb  = wv & 3;           // row-band wave 0..3
    const int h = blockIdx.x;
    const _Float16* g = mats + (size_t)h * 20480;
    const int col = lane & 15, qd = lane >> 4;
    const int band = wb * 16;
    const int uRo = USB + grp * 18432;
    const int uIo = uRo + 9216;

    // ---- stage all 5 mats (40KB) into padded LDS, once per block ----
#pragma unroll
    for (int it = 0; it < 3; ++it) {
        const int chunk = it * 1024 + tid;   // 16B units, 0..2559
        if (chunk < 2560) {
            const int m = chunk >> 9;
            const int rem = chunk & 511;
            const int r = rem >> 3, c16 = rem & 7;
            *(uint4*)(sm + m * 9216 + r * 144 + c16 * 16) =
                *(const uint4*)(g + (size_t)chunk * 8);
        }
    }

    const float Dp1 = 1.0f + Dp[h];
    float swR = 0.0f, swI = 0.0f;
    if (lane < 16) {
        swR = wwR[h * 64 + band + lane];
        swI = wwI[h * 64 + band + lane];
    }
    float* xr = xt + ((size_t)grp * Hh + h) * Lseq;
    __syncthreads();  // mats staged

    // ---- phase 1: u = X @ U^T (complex); X from global -> registers ----
    f16x8 axk[2];
    f32x4v aR[4] = {}, aI[4] = {};
#pragma unroll
    for (int kh2 = 0; kh2 < 2; ++kh2) {
        const int kk = kh2 * 32;
        const float* xp = xr + (band + col) * 64 + kk + qd * 8;
        const float4 v0 = *(const float4*)(xp);
        const float4 v1 = *(const float4*)(xp + 4);
        f16x8 a;
        a[0] = (_Float16)v0.x; a[1] = (_Float16)v0.y;
        a[2] = (_Float16)v0.z; a[3] = (_Float16)v0.w;
        a[4] = (_Float16)v1.x; a[5] = (_Float16)v1.y;
        a[6] = (_Float16)v1.z; a[7] = (_Float16)v1.w;
        axk[kh2] = a;
#pragma unroll
        for (int nt = 0; nt < 4; ++nt) {
            aR[nt] = __builtin_amdgcn_mfma_f32_16x16x32_f16(
                a, LFRAG(MR0, nt * 16, kk), aR[nt], 0, 0, 0);
            aI[nt] = __builtin_amdgcn_mfma_f32_16x16x32_f16(
                a, LFRAG(MI0, nt * 16, kk), aI[nt], 0, 0, 0);
        }
    }
#pragma unroll
    for (int nt = 0; nt < 4; ++nt)
#pragma unroll
        for (int rg = 0; rg < 4; ++rg) {
            const int cc = band + qd * 4 + rg, n = nt * 16 + col;
            *(_Float16*)(sm + uRo + cc * 144 + n * 2) = (_Float16)aR[nt][rg];
            *(_Float16*)(sm + uIo + cc * 144 + n * 2) = (_Float16)aI[nt][rg];
        }
    __syncthreads();  // u visible

    // ---- phase 2: chunk-level scan, in-place u->S; wave owns 16 n ----
    if (lane < 16) {
        const int n = band + lane;
        float sR = 0.0f, sI = 0.0f;
        for (int c = 0; c < 64; ++c) {
            _Float16* pR = (_Float16*)(sm + uRo + c * 144 + n * 2);
            _Float16* pI = (_Float16*)(sm + uIo + c * 144 + n * 2);
            const float uRv = (float)*pR;
            const float uIv = (float)*pI;
            *pR = (_Float16)sR;
            *pI = (_Float16)sI;
            const float nR = fmaf(swR, sR, fmaf(-swI, sI, uRv));
            sI = fmaf(swR, sI, fmaf(swI, sR, uIv));
            sR = nR;
        }
    }
    __syncthreads();  // S visible

    // ---- phase 3: y = X@M1^T + SR@PR^T + SI@PIneg^T ----
    f32x4v acc[4] = {};
#pragma unroll
    for (int kh2 = 0; kh2 < 2; ++kh2) {
        const int kk = kh2 * 32;
#pragma unroll
        for (int tt = 0; tt < 4; ++tt)
            acc[tt] = __builtin_amdgcn_mfma_f32_16x16x32_f16(
                axk[kh2], LFRAG(MM1, tt * 16, kk), acc[tt], 0, 0, 0);
    }
#pragma unroll
    for (int kh2 = 0; kh2 < 2; ++kh2) {
        const int kk = kh2 * 32;
        const f16x8 as = LFRAG(uRo, band, kk);
#pragma unroll
        for (int tt = 0; tt < 4; ++tt)
            acc[tt] = __builtin_amdgcn_mfma_f32_16x16x32_f16(
                as, LFRAG(MPR, tt * 16, kk), acc[tt], 0, 0, 0);
    }
#pragma unroll
    for (int kh2 = 0; kh2 < 2; ++kh2) {
        const int kk = kh2 * 32;
        const f16x8 az = LFRAG(uIo, band, kk);
#pragma unroll
        for (int tt = 0; tt < 4; ++tt)
            acc[tt] = __builtin_amdgcn_mfma_f32_16x16x32_f16(
                az, LFRAG(MPI, tt * 16, kk), acc[tt], 0, 0, 0);
    }

    // ---- epilogue: r = x*(1+D) + y, straight from accumulators ----
#pragma unroll
    for (int tt = 0; tt < 4; ++tt)
#pragma unroll
        for (int rg = 0; rg < 4; ++rg) {
            const int l = (band + qd * 4 + rg) * 64 + tt * 16 + col;
            xr[l] = fmaf(xr[l], Dp1, acc[tt][rg]);
        }
}

// ---------------------------------------------------------------------------
// K3: single-pass LayerNorm + transpose back: rt [B,H,L] -> out [B,L,H].
// tile stride 1033 (odd): LDS write aliasing 4-way -> ~2-way.
// ---------------------------------------------------------------------------
__global__ __launch_bounds__(512, 2) void k_ln(const float* __restrict__ rt,
                                               float* __restrict__ out,
                                               const float* __restrict__ lnw,
                                               const float* __restrict__ lnb) {
    __shared__ float tile[16 * 1033];
    __shared__ float ps[32][17], pq[32][17];
    __shared__ float mm[16], rs[16];
    const int b  = blockIdx.y;
    const int l0 = blockIdx.x * 16;
    const int tid = threadIdx.x;
    const int ll = tid & 15;
    const int hh = tid >> 4;  // 0..31

    const float* base = rt + (size_t)b * Hh * Lseq + l0;

    float psum = 0.0f, psq = 0.0f;
#pragma unroll 8
    for (int hc = 0; hc < Hh; hc += 32) {
        const float v = base[(size_t)(hc + hh) * Lseq + ll];
        tile[ll * 1033 + hc + hh] = v;
        psum += v;
        psq = fmaf(v, v, psq);
    }
    ps[hh][ll] = psum;
    pq[hh][ll] = psq;
    __syncthreads();
    if (tid < 16) {
        float s = 0.f, q = 0.f;
#pragma unroll
        for (int k = 0; k < 32; ++k) {
            s += ps[k][tid];
            q += pq[k][tid];
        }
        const float mu  = s * (1.0f / Hh);
        const float var = fmaf(-mu, mu, q * (1.0f / Hh));
        mm[tid] = mu;
        rs[tid] = rsqrtf(var + LN_EPS);
    }
    __syncthreads();

    const float w0 = lnw[tid],       b0 = lnb[tid];
    const float w1 = lnw[512 + tid], b1 = lnb[512 + tid];
    float* obase = out + ((size_t)b * Lseq + l0) * Hh;
#pragma unroll 4
    for (int l = 0; l < 16; ++l) {
        const float mu = mm[l], rsg = rs[l];
        const float v0 = tile[l * 1033 + tid];
        const float v1 = tile[l * 1033 + 512 + tid];
        obase[(size_t)l * Hh + tid]       = fmaf((v0 - mu) * rsg, w0, b0);
        obase[(size_t)l * Hh + 512 + tid] = fmaf((v1 - mu) * rsg, w1, b1);
    }
}

// ---------------------------------------------------------------------------
extern "C" void kernel_launch(void* const* d_in, const int* in_sizes, int n_in,
                              void* d_out, int out_size, void* d_ws, size_t ws_size,
                              hipStream_t stream) {
    const float* x     = (const float*)d_in[0];
    const float* logA  = (const float*)d_in[1];
    const float* Aim   = (const float*)d_in[2];
    const float* Cre   = (const float*)d_in[3];
    const float* Cim   = (const float*)d_in[4];
    const float* logdt = (const float*)d_in[5];
    const float* Dp    = (const float*)d_in[6];
    const float* lnw   = (const float*)d_in[7];
    const float* lnb   = (const float*)d_in[8];
    float* out = (float*)d_out;
    float* ws  = (float*)d_ws;  // 64 MiB: xt/r [B,H,L]

    _Float16* mats = (_Float16*)d_out;                          // 40 MiB
    float* wwR = (float*)((char*)d_out + 41943040);             // 256 KiB
    float* wwI = (float*)((char*)d_out + 42205184);             // 256 KiB

    k_precompute<<<dim3(Hh), 256, 0, stream>>>(logA, Aim, Cre, Cim, logdt,
                                               mats, wwR, wwI);
    k_transpose<<<dim3(Hh / 64, Lseq / 64, Bb), 256, 0, stream>>>(x, ws);
    k_chunk<<<dim3(Hh), 1024, 0, stream>>>(ws, mats, wwR, wwI, Dp);
    k_ln<<<dim3(Lseq / 16, Bb), 512, 0, stream>>>(ws, out, lnw, lnb);
}